// Round 4
// baseline (1511.681 us; speedup 1.0000x reference)
//
#include <hip/hip_runtime.h>

#define GN 100000
#define GE 1600000
#define NEPS 6400000

// ---------------- threefry2x32 (JAX-compatible) ----------------
__device__ __forceinline__ unsigned rotl32(unsigned x, int r) { return (x << r) | (x >> (32 - r)); }

__device__ __forceinline__ void threefry2x32(unsigned k0, unsigned k1,
                                             unsigned c0, unsigned c1,
                                             unsigned& o0, unsigned& o1) {
  const unsigned ks2 = k0 ^ k1 ^ 0x1BD11BDAu;
  unsigned x0 = c0 + k0, x1 = c1 + k1;
#define TF_R4(ra, rb, rc, rd) \
  x0 += x1; x1 = rotl32(x1, ra); x1 ^= x0; \
  x0 += x1; x1 = rotl32(x1, rb); x1 ^= x0; \
  x0 += x1; x1 = rotl32(x1, rc); x1 ^= x0; \
  x0 += x1; x1 = rotl32(x1, rd); x1 ^= x0;
  TF_R4(13, 15, 26, 6)  x0 += k1;  x1 += ks2 + 1u;
  TF_R4(17, 29, 16, 24) x0 += ks2; x1 += k0 + 2u;
  TF_R4(13, 15, 26, 6)  x0 += k0;  x1 += k1 + 3u;
  TF_R4(17, 29, 16, 24) x0 += k1;  x1 += ks2 + 4u;
  TF_R4(13, 15, 26, 6)  x0 += ks2; x1 += k0 + 5u;
#undef TF_R4
  o0 = x0; o1 = x1;
}

// uniform bits -> N(0,1) exactly as jax.random.normal (XLA erfinv polynomial)
__device__ __forceinline__ float bits_to_normal(unsigned bits) {
  const float lo = -0.99999994f;  // nextafter(-1, 0)
  const float u = __uint_as_float((bits >> 9) | 0x3f800000u) - 1.0f;  // [0,1)
  float x = u * 2.0f + lo;        // maxval-minval rounds to exactly 2.0f
  x = fmaxf(x, lo);
  float w = -log1pf(-x * x);
  float p;
  if (w < 5.0f) {
    w -= 2.5f;
    p = 2.81022636e-08f;
    p = fmaf(p, w, 3.43273939e-07f);
    p = fmaf(p, w, -3.5233877e-06f);
    p = fmaf(p, w, -4.39150654e-06f);
    p = fmaf(p, w, 0.00021858087f);
    p = fmaf(p, w, -0.00125372503f);
    p = fmaf(p, w, -0.00417768164f);
    p = fmaf(p, w, 0.246640727f);
    p = fmaf(p, w, 1.50140941f);
  } else {
    w = sqrtf(w) - 3.0f;
    p = -0.000200214257f;
    p = fmaf(p, w, 0.000100950558f);
    p = fmaf(p, w, 0.00134934322f);
    p = fmaf(p, w, -0.00367342844f);
    p = fmaf(p, w, 0.00573950773f);
    p = fmaf(p, w, -0.0076224613f);
    p = fmaf(p, w, 0.00943887047f);
    p = fmaf(p, w, 1.00167406f);
    p = fmaf(p, w, 2.83297682f);
  }
  return 1.41421356f * p * x;
}

// ---------------- CSR build ----------------
__global__ void hist_kernel(const int* __restrict__ dst, int* __restrict__ hist) {
  const int e = blockIdx.x * 256 + threadIdx.x;
  if (e < GE) atomicAdd(&hist[dst[e]], 1);
}

__global__ __launch_bounds__(1024) void scan_kernel(const int* __restrict__ hist,
                                                    int* __restrict__ row_ptr) {
  __shared__ int wsum[16];
  __shared__ int carry_s;
  const int t = threadIdx.x, lane = t & 63, wave = t >> 6;
  if (t == 0) carry_s = 0;
  __syncthreads();
  for (int base = 0; base < GN; base += 4096) {
    const int idx = base + t * 4;
    const int h0 = (idx + 0 < GN) ? hist[idx + 0] : 0;
    const int h1 = (idx + 1 < GN) ? hist[idx + 1] : 0;
    const int h2 = (idx + 2 < GN) ? hist[idx + 2] : 0;
    const int h3 = (idx + 3 < GN) ? hist[idx + 3] : 0;
    const int p0 = h0, p1 = h0 + h1, p2 = h0 + h1 + h2, p3 = h0 + h1 + h2 + h3;
    int s = p3;
#pragma unroll
    for (int o = 1; o < 64; o <<= 1) {
      const int u = __shfl_up(s, o, 64);
      if (lane >= o) s += u;
    }
    if (lane == 63) wsum[wave] = s;
    __syncthreads();
    int woff = 0;
    for (int w2 = 0; w2 < wave; w2++) woff += wsum[w2];
    const int carry = carry_s;
    __syncthreads();
    const int tb = carry + woff + (s - p3);  // exclusive base for this thread
    if (idx + 0 < GN) row_ptr[idx + 0] = tb;
    if (idx + 1 < GN) row_ptr[idx + 1] = tb + p0;
    if (idx + 2 < GN) row_ptr[idx + 2] = tb + p1;
    if (idx + 3 < GN) row_ptr[idx + 3] = tb + p2;
    if (t == 1023) carry_s = carry + woff + s;
    __syncthreads();
  }
  if (t == 0) row_ptr[GN] = carry_s;
}

__global__ void norm_kernel(const int* __restrict__ hist,
                            float* __restrict__ norm1, float* __restrict__ norm2) {
  const int i = blockIdx.x * 256 + threadIdx.x;
  if (i < GN) {
    const double d = (double)max(hist[i], 1);
    const double n1 = 1.0 / sqrt(d);
    norm1[i] = (float)n1;
    norm2[i] = (float)(1.0 / d);
  }
}

__global__ void fill_kernel(const int* __restrict__ src, const int* __restrict__ dst,
                            const int* __restrict__ row_ptr, int* __restrict__ fillc,
                            int* __restrict__ csr) {
  const int e = blockIdx.x * 256 + threadIdx.x;
  if (e < GE) {
    const int d = dst[e];
    const int pos = atomicAdd(&fillc[d], 1);
    csr[row_ptr[d] + pos] = src[e];
  }
}

// ---------------- layer 1 GEMM (f64 accumulate) + epilogue ----------------
#define DFMA8(acc, a, p0, p1)                                                       \
  acc[0] = fma(a, (double)p0.x, acc[0]); acc[1] = fma(a, (double)p0.y, acc[1]);     \
  acc[2] = fma(a, (double)p0.z, acc[2]); acc[3] = fma(a, (double)p0.w, acc[3]);     \
  acc[4] = fma(a, (double)p1.x, acc[4]); acc[5] = fma(a, (double)p1.y, acc[5]);     \
  acc[6] = fma(a, (double)p1.z, acc[6]); acc[7] = fma(a, (double)p1.w, acc[7]);

__global__ __launch_bounds__(256) void gemm1_kernel(
    const float* __restrict__ x,
    const float* __restrict__ wm, const float* __restrict__ wv,
    const float* __restrict__ bm, const float* __restrict__ bv,
    const float* __restrict__ norm1, const float* __restrict__ norm2,
    float* __restrict__ m_pre, float* __restrict__ v_pre) {
  __shared__ float xs[32][36];       // padded: 16B-aligned rows
  __shared__ float wms[32][128];
  __shared__ float wvs[32][128];
  const int t = threadIdx.x;
  const int row0 = blockIdx.x * 32;
  const int ty = t >> 4, tx = t & 15;  // rows ty*2+{0,1}, cols {tx*4..+3, tx*4+64..+67}
  double accm[2][8] = {};
  double accv[2][8] = {};
  for (int k0 = 0; k0 < 256; k0 += 32) {
    {
      const int r = t >> 3, c4 = (t & 7) << 2;
      *(float4*)&xs[r][c4] = *(const float4*)&x[(size_t)(row0 + r) * 256 + k0 + c4];
    }
#pragma unroll
    for (int i = 0; i < 4; i++) {
      const int f = t + (i << 8);           // float4 index 0..1023
      const int kk = f >> 5, j4 = (f & 31) << 2;
      *(float4*)&wms[kk][j4] = *(const float4*)&wm[(size_t)(k0 + kk) * 128 + j4];
      *(float4*)&wvs[kk][j4] = *(const float4*)&wv[(size_t)(k0 + kk) * 128 + j4];
    }
    __syncthreads();
#pragma unroll 4
    for (int kk = 0; kk < 32; kk++) {
      const double a0 = (double)xs[ty * 2 + 0][kk];
      const double a1 = (double)xs[ty * 2 + 1][kk];
      const float4 bm0 = *(const float4*)&wms[kk][tx * 4];
      const float4 bm1 = *(const float4*)&wms[kk][tx * 4 + 64];
      const float4 bv0 = *(const float4*)&wvs[kk][tx * 4];
      const float4 bv1 = *(const float4*)&wvs[kk][tx * 4 + 64];
      DFMA8(accm[0], a0, bm0, bm1)
      DFMA8(accm[1], a1, bm0, bm1)
      DFMA8(accv[0], a0, bv0, bv1)
      DFMA8(accv[1], a1, bv0, bv1)
    }
    __syncthreads();
  }
  float bmv[8], bvv[8];
#pragma unroll
  for (int j = 0; j < 4; j++) {
    bmv[j] = bm[tx * 4 + j];      bmv[4 + j] = bm[tx * 4 + 64 + j];
    bvv[j] = bv[tx * 4 + j];      bvv[4 + j] = bv[tx * 4 + 64 + j];
  }
#pragma unroll
  for (int rr = 0; rr < 2; rr++) {
    const int i = row0 + ty * 2 + rr;
    const float n1 = norm1[i], n2 = norm2[i];
    float om[8], ov[8];
#pragma unroll
    for (int j = 0; j < 8; j++) {
      const float mean = fmaxf((float)accm[rr][j] + bmv[j], 0.f);
      const float var  = fmaxf((float)accv[rr][j] + bvv[j], 0.f);
      const float att = expf(-var);          // gamma = 1
      om[j] = mean * att * n1;
      ov[j] = var * att * att * n2;
    }
    float4 s4;
    s4.x = om[0]; s4.y = om[1]; s4.z = om[2]; s4.w = om[3];
    *(float4*)&m_pre[(size_t)i * 128 + tx * 4] = s4;
    s4.x = om[4]; s4.y = om[5]; s4.z = om[6]; s4.w = om[7];
    *(float4*)&m_pre[(size_t)i * 128 + tx * 4 + 64] = s4;
    s4.x = ov[0]; s4.y = ov[1]; s4.z = ov[2]; s4.w = ov[3];
    *(float4*)&v_pre[(size_t)i * 128 + tx * 4] = s4;
    s4.x = ov[4]; s4.y = ov[5]; s4.z = ov[6]; s4.w = ov[7];
    *(float4*)&v_pre[(size_t)i * 128 + tx * 4 + 64] = s4;
  }
}

// ---------------- aggregate layer1 (f64) + layer2 GEMM (f64 acc) ----------------
__global__ __launch_bounds__(256) void agg1_gemm2_kernel(
    const int* __restrict__ row_ptr, const int* __restrict__ csr,
    const float* __restrict__ m_pre, const float* __restrict__ v_pre,
    const float* __restrict__ wm2, const float* __restrict__ wv2,
    const float* __restrict__ bm2, const float* __restrict__ bv2,
    const float* __restrict__ norm1, const float* __restrict__ norm2,
    float* __restrict__ m2_pre, float* __restrict__ v2_pre) {
  __shared__ float hm[32][130];
  __shared__ float hv[32][130];
  __shared__ float wsh[2][64][64];
  const int t = threadIdx.x;
  const int wave = t >> 6, lane = t & 63;
  const int nbase = blockIdx.x * 32;

  // Phase A: wave-per-node gather+sum (8 nodes per wave), f64 accumulate
  for (int q = 0; q < 8; q++) {
    const int li = wave * 8 + q;
    const int i = nbase + li;
    const int e0 = row_ptr[i], e1 = row_ptr[i + 1];
    double amx = 0., amy = 0., avx = 0., avy = 0.;
    for (int e = e0; e < e1; e++) {
      const int s = csr[e];
      const float2 mm = *(const float2*)&m_pre[s * 128 + lane * 2];
      const float2 vv = *(const float2*)&v_pre[s * 128 + lane * 2];
      amx += (double)mm.x; amy += (double)mm.y;
      avx += (double)vv.x; avy += (double)vv.y;
    }
    const double n1 = (double)norm1[i], n2 = (double)norm2[i];
    float2 hmv, hvv;
    hmv.x = (float)fmax(amx * n1, 0.); hmv.y = (float)fmax(amy * n1, 0.);
    hvv.x = (float)fmax(avx * n2, 0.); hvv.y = (float)fmax(avy * n2, 0.);
    *(float2*)&hm[li][lane * 2] = hmv;
    *(float2*)&hv[li][lane * 2] = hvv;
  }
  __syncthreads();

  // Phase B: 32x128 @ 128x64 (x2), f64 accumulate
  const int r = t >> 3;           // 0..31
  const int c0 = (t & 7) << 3;    // 0..56
  double accm[8] = {};
  double accv[8] = {};
  for (int kc = 0; kc < 2; kc++) {
#pragma unroll
    for (int ii = 0; ii < 4; ii++) {
      const int f4 = t + (ii << 8);     // 0..1023
      const int k = f4 >> 4, j4 = (f4 & 15) << 2;
      *(float4*)&wsh[0][k][j4] = *(const float4*)&wm2[(size_t)(kc * 64 + k) * 64 + j4];
      *(float4*)&wsh[1][k][j4] = *(const float4*)&wv2[(size_t)(kc * 64 + k) * 64 + j4];
    }
    __syncthreads();
#pragma unroll 4
    for (int kk = 0; kk < 64; kk++) {
      const double am = (double)hm[r][kc * 64 + kk];
      const double av = (double)hv[r][kc * 64 + kk];
      const float4 b0 = *(const float4*)&wsh[0][kk][c0];
      const float4 b1 = *(const float4*)&wsh[0][kk][c0 + 4];
      const float4 d0 = *(const float4*)&wsh[1][kk][c0];
      const float4 d1 = *(const float4*)&wsh[1][kk][c0 + 4];
      DFMA8(accm, am, b0, b1)
      DFMA8(accv, av, d0, d1)
    }
    __syncthreads();
  }
  const int i = nbase + r;
  const float n1 = norm1[i], n2 = norm2[i];
  float om[8], ov[8];
#pragma unroll
  for (int j = 0; j < 8; j++) {
    const float mean2 = fmaxf((float)accm[j] + bm2[c0 + j], 0.f);
    const float var2  = fmaxf((float)accv[j] + bv2[c0 + j], 0.f);
    const float att = expf(-var2);
    om[j] = mean2 * att * n1;
    ov[j] = var2 * att * att * n2;
  }
  float4 s4;
  s4.x = om[0]; s4.y = om[1]; s4.z = om[2]; s4.w = om[3];
  *(float4*)&m2_pre[i * 64 + c0] = s4;
  s4.x = om[4]; s4.y = om[5]; s4.z = om[6]; s4.w = om[7];
  *(float4*)&m2_pre[i * 64 + c0 + 4] = s4;
  s4.x = ov[0]; s4.y = ov[1]; s4.z = ov[2]; s4.w = ov[3];
  *(float4*)&v2_pre[i * 64 + c0] = s4;
  s4.x = ov[4]; s4.y = ov[5]; s4.z = ov[6]; s4.w = ov[7];
  *(float4*)&v2_pre[i * 64 + c0 + 4] = s4;
}

// ---------------- aggregate layer 2 (f64) ----------------
__global__ __launch_bounds__(256) void agg2_kernel(
    const int* __restrict__ row_ptr, const int* __restrict__ csr,
    const float* __restrict__ m2_pre, const float* __restrict__ v2_pre,
    const float* __restrict__ norm1, const float* __restrict__ norm2,
    float* __restrict__ mean_o, float* __restrict__ var_o) {
  const int wave = threadIdx.x >> 6, lane = threadIdx.x & 63;
  const int i = blockIdx.x * 4 + wave;
  const int e0 = row_ptr[i], e1 = row_ptr[i + 1];
  double am = 0., av = 0.;
  for (int e = e0; e < e1; e++) {
    const int s = csr[e];
    am += (double)m2_pre[s * 64 + lane];
    av += (double)v2_pre[s * 64 + lane];
  }
  mean_o[i * 64 + lane] = (float)(am * (double)norm1[i]);
  var_o[i * 64 + lane]  = (float)(av * (double)norm2[i]);
}

// ---------------- reparameterization ----------------
// eps matches jax.random.normal(key(42), (GN,64)) with jax_threefry_partitionable=True
// (modern JAX default): per element i, counter=(hi,lo)=(0,i) via iota_2x32_shape,
// bits = o0 ^ o1, then the standard uniform->erfinv mapping.
__global__ void reparam_kernel(const float* __restrict__ mean_o,
                               const float* __restrict__ var_o,
                               float* __restrict__ out) {
  const int b = blockIdx.x * 256 + threadIdx.x;   // 0 .. NEPS-1 (grid exact)
  unsigned o0, o1;
  threefry2x32(0u, 42u, 0u, (unsigned)b, o0, o1);
  const float eps = bits_to_normal(o0 ^ o1);
  out[b] = eps * sqrtf(var_o[b] + 1e-8f) + mean_o[b];
}

// ---------------- launch ----------------
extern "C" void kernel_launch(void* const* d_in, const int* in_sizes, int n_in,
                              void* d_out, int out_size, void* d_ws, size_t ws_size,
                              hipStream_t stream) {
  (void)in_sizes; (void)n_in; (void)out_size; (void)ws_size;
  const float* x   = (const float*)d_in[0];
  const int*   src = (const int*)d_in[1];
  const int*   dst = (const int*)d_in[2];
  const float* wm1 = (const float*)d_in[3];
  const float* wv1 = (const float*)d_in[4];
  const float* bm1 = (const float*)d_in[5];
  const float* bv1 = (const float*)d_in[6];
  const float* wm2 = (const float*)d_in[7];
  const float* wv2 = (const float*)d_in[8];
  const float* bm2 = (const float*)d_in[9];
  const float* bv2 = (const float*)d_in[10];
  float* out = (float*)d_out;

  char* base = (char*)d_ws;
  size_t off = 0;
  auto alloc = [&](size_t bytes) -> void* {
    void* p = base + off;
    off += (bytes + 255) & ~(size_t)255;
    return p;
  };
  int*   hist    = (int*)alloc((size_t)GN * 4);
  int*   row_ptr = (int*)alloc((size_t)(GN + 1) * 4);
  int*   fillc   = (int*)alloc((size_t)GN * 4);
  int*   csr     = (int*)alloc((size_t)GE * 4);
  float* norm1   = (float*)alloc((size_t)GN * 4);
  float* norm2   = (float*)alloc((size_t)GN * 4);
  float* m_pre   = (float*)alloc((size_t)GN * 128 * 4);
  float* v_pre   = (float*)alloc((size_t)GN * 128 * 4);
  float* m2_pre  = (float*)alloc((size_t)GN * 64 * 4);
  float* v2_pre  = (float*)alloc((size_t)GN * 64 * 4);
  float* mean_o  = m_pre;                       // m_pre/v_pre dead after agg1_gemm2
  float* var_o   = m_pre + (size_t)GN * 64;

  hipMemsetAsync(hist, 0, (size_t)GN * 4, stream);
  hipMemsetAsync(fillc, 0, (size_t)GN * 4, stream);

  hist_kernel<<<(GE + 255) / 256, 256, 0, stream>>>(dst, hist);
  scan_kernel<<<1, 1024, 0, stream>>>(hist, row_ptr);
  norm_kernel<<<(GN + 255) / 256, 256, 0, stream>>>(hist, norm1, norm2);
  fill_kernel<<<(GE + 255) / 256, 256, 0, stream>>>(src, dst, row_ptr, fillc, csr);
  gemm1_kernel<<<GN / 32, 256, 0, stream>>>(x, wm1, wv1, bm1, bv1, norm1, norm2, m_pre, v_pre);
  agg1_gemm2_kernel<<<GN / 32, 256, 0, stream>>>(row_ptr, csr, m_pre, v_pre,
                                                 wm2, wv2, bm2, bv2, norm1, norm2,
                                                 m2_pre, v2_pre);
  agg2_kernel<<<GN / 4, 256, 0, stream>>>(row_ptr, csr, m2_pre, v2_pre, norm1, norm2, mean_o, var_o);
  reparam_kernel<<<NEPS / 256, 256, 0, stream>>>(mean_o, var_o, out);
}

// Round 5
// 816.884 us; speedup vs baseline: 1.8505x; 1.8505x over previous
//
#include <hip/hip_runtime.h>

#define GN 100000
#define GE 1600000

// ---------------- bf16 pack/unpack ----------------
__device__ __forceinline__ unsigned bf16r(float f) {      // f32 -> bf16 bits (RNE)
  unsigned u = __float_as_uint(f);
  return (u + 0x7FFFu + ((u >> 16) & 1u)) >> 16;
}
__device__ __forceinline__ unsigned pack2(float lo, float hi) {
  return bf16r(lo) | (bf16r(hi) << 16);
}
__device__ __forceinline__ float bflo(unsigned u) { return __uint_as_float(u << 16); }
__device__ __forceinline__ float bfhi(unsigned u) { return __uint_as_float(u & 0xFFFF0000u); }

// ---------------- threefry2x32 (JAX-compatible) ----------------
__device__ __forceinline__ unsigned rotl32(unsigned x, int r) { return (x << r) | (x >> (32 - r)); }

__device__ __forceinline__ void threefry2x32(unsigned k0, unsigned k1,
                                             unsigned c0, unsigned c1,
                                             unsigned& o0, unsigned& o1) {
  const unsigned ks2 = k0 ^ k1 ^ 0x1BD11BDAu;
  unsigned x0 = c0 + k0, x1 = c1 + k1;
#define TF_R4(ra, rb, rc, rd) \
  x0 += x1; x1 = rotl32(x1, ra); x1 ^= x0; \
  x0 += x1; x1 = rotl32(x1, rb); x1 ^= x0; \
  x0 += x1; x1 = rotl32(x1, rc); x1 ^= x0; \
  x0 += x1; x1 = rotl32(x1, rd); x1 ^= x0;
  TF_R4(13, 15, 26, 6)  x0 += k1;  x1 += ks2 + 1u;
  TF_R4(17, 29, 16, 24) x0 += ks2; x1 += k0 + 2u;
  TF_R4(13, 15, 26, 6)  x0 += k0;  x1 += k1 + 3u;
  TF_R4(17, 29, 16, 24) x0 += k1;  x1 += ks2 + 4u;
  TF_R4(13, 15, 26, 6)  x0 += ks2; x1 += k0 + 5u;
#undef TF_R4
  o0 = x0; o1 = x1;
}

// uniform bits -> N(0,1) exactly as jax.random.normal (XLA erfinv polynomial)
__device__ __forceinline__ float bits_to_normal(unsigned bits) {
  const float lo = -0.99999994f;  // nextafter(-1, 0)
  const float u = __uint_as_float((bits >> 9) | 0x3f800000u) - 1.0f;  // [0,1)
  float x = u * 2.0f + lo;
  x = fmaxf(x, lo);
  float w = -log1pf(-x * x);
  float p;
  if (w < 5.0f) {
    w -= 2.5f;
    p = 2.81022636e-08f;
    p = fmaf(p, w, 3.43273939e-07f);
    p = fmaf(p, w, -3.5233877e-06f);
    p = fmaf(p, w, -4.39150654e-06f);
    p = fmaf(p, w, 0.00021858087f);
    p = fmaf(p, w, -0.00125372503f);
    p = fmaf(p, w, -0.00417768164f);
    p = fmaf(p, w, 0.246640727f);
    p = fmaf(p, w, 1.50140941f);
  } else {
    w = sqrtf(w) - 3.0f;
    p = -0.000200214257f;
    p = fmaf(p, w, 0.000100950558f);
    p = fmaf(p, w, 0.00134934322f);
    p = fmaf(p, w, -0.00367342844f);
    p = fmaf(p, w, 0.00573950773f);
    p = fmaf(p, w, -0.0076224613f);
    p = fmaf(p, w, 0.00943887047f);
    p = fmaf(p, w, 1.00167406f);
    p = fmaf(p, w, 2.83297682f);
  }
  return 1.41421356f * p * x;
}

// ---------------- CSR build ----------------
__global__ void hist_kernel(const int* __restrict__ dst, int* __restrict__ hist) {
  const int e = blockIdx.x * 256 + threadIdx.x;
  if (e < GE) atomicAdd(&hist[dst[e]], 1);
}

__global__ __launch_bounds__(1024) void scan_kernel(const int* __restrict__ hist,
                                                    int* __restrict__ row_ptr) {
  __shared__ int wsum[16];
  __shared__ int carry_s;
  const int t = threadIdx.x, lane = t & 63, wave = t >> 6;
  if (t == 0) carry_s = 0;
  __syncthreads();
  for (int base = 0; base < GN; base += 4096) {
    const int idx = base + t * 4;
    const int h0 = (idx + 0 < GN) ? hist[idx + 0] : 0;
    const int h1 = (idx + 1 < GN) ? hist[idx + 1] : 0;
    const int h2 = (idx + 2 < GN) ? hist[idx + 2] : 0;
    const int h3 = (idx + 3 < GN) ? hist[idx + 3] : 0;
    const int p0 = h0, p1 = h0 + h1, p2 = h0 + h1 + h2, p3 = h0 + h1 + h2 + h3;
    int s = p3;
#pragma unroll
    for (int o = 1; o < 64; o <<= 1) {
      const int u = __shfl_up(s, o, 64);
      if (lane >= o) s += u;
    }
    if (lane == 63) wsum[wave] = s;
    __syncthreads();
    int woff = 0;
    for (int w2 = 0; w2 < wave; w2++) woff += wsum[w2];
    const int carry = carry_s;
    __syncthreads();
    const int tb = carry + woff + (s - p3);  // exclusive base for this thread
    if (idx + 0 < GN) row_ptr[idx + 0] = tb;
    if (idx + 1 < GN) row_ptr[idx + 1] = tb + p0;
    if (idx + 2 < GN) row_ptr[idx + 2] = tb + p1;
    if (idx + 3 < GN) row_ptr[idx + 3] = tb + p2;
    if (t == 1023) carry_s = carry + woff + s;
    __syncthreads();
  }
  if (t == 0) row_ptr[GN] = carry_s;
}

__global__ void norm_kernel(const int* __restrict__ hist,
                            float* __restrict__ norm1, float* __restrict__ norm2) {
  const int i = blockIdx.x * 256 + threadIdx.x;
  if (i < GN) {
    const double d = (double)max(hist[i], 1);
    norm1[i] = (float)(1.0 / sqrt(d));
    norm2[i] = (float)(1.0 / d);
  }
}

__global__ void fill_kernel(const int* __restrict__ src, const int* __restrict__ dst,
                            const int* __restrict__ row_ptr, int* __restrict__ fillc,
                            int* __restrict__ csr) {
  const int e = blockIdx.x * 256 + threadIdx.x;
  if (e < GE) {
    const int d = dst[e];
    const int pos = atomicAdd(&fillc[d], 1);
    csr[row_ptr[d] + pos] = src[e];
  }
}

// ---------------- layer 1 GEMM (f32) + epilogue -> packed bf16 messages ----------------
// mv16 layout: per node i, 64 pairs; pair p (features 2p,2p+1) = 2 uints:
//   uint[2p]   = bf16(m_{2p}) | bf16(m_{2p+1})<<16
//   uint[2p+1] = bf16(v_{2p}) | bf16(v_{2p+1})<<16
#define FMA8(acc, a, p0, p1)                                                        \
  acc[0] = fmaf(a, p0.x, acc[0]); acc[1] = fmaf(a, p0.y, acc[1]);                   \
  acc[2] = fmaf(a, p0.z, acc[2]); acc[3] = fmaf(a, p0.w, acc[3]);                   \
  acc[4] = fmaf(a, p1.x, acc[4]); acc[5] = fmaf(a, p1.y, acc[5]);                   \
  acc[6] = fmaf(a, p1.z, acc[6]); acc[7] = fmaf(a, p1.w, acc[7]);

__global__ __launch_bounds__(256) void gemm1_kernel(
    const float* __restrict__ x,
    const float* __restrict__ wm, const float* __restrict__ wv,
    const float* __restrict__ bm, const float* __restrict__ bv,
    const float* __restrict__ norm1, const float* __restrict__ norm2,
    unsigned* __restrict__ mv16) {
  __shared__ float xs[32][36];
  __shared__ float wms[32][128];
  __shared__ float wvs[32][128];
  const int t = threadIdx.x;
  const int row0 = blockIdx.x * 32;
  const int ty = t >> 4, tx = t & 15;  // rows ty*2+{0,1}, cols {tx*4..+3, tx*4+64..+67}
  float accm[2][8] = {};
  float accv[2][8] = {};
  for (int k0 = 0; k0 < 256; k0 += 32) {
    {
      const int r = t >> 3, c4 = (t & 7) << 2;
      *(float4*)&xs[r][c4] = *(const float4*)&x[(size_t)(row0 + r) * 256 + k0 + c4];
    }
#pragma unroll
    for (int i = 0; i < 4; i++) {
      const int f = t + (i << 8);           // float4 index 0..1023
      const int kk = f >> 5, j4 = (f & 31) << 2;
      *(float4*)&wms[kk][j4] = *(const float4*)&wm[(size_t)(k0 + kk) * 128 + j4];
      *(float4*)&wvs[kk][j4] = *(const float4*)&wv[(size_t)(k0 + kk) * 128 + j4];
    }
    __syncthreads();
#pragma unroll 8
    for (int kk = 0; kk < 32; kk++) {
      const float a0 = xs[ty * 2 + 0][kk];
      const float a1 = xs[ty * 2 + 1][kk];
      const float4 bm0 = *(const float4*)&wms[kk][tx * 4];
      const float4 bm1 = *(const float4*)&wms[kk][tx * 4 + 64];
      const float4 bv0 = *(const float4*)&wvs[kk][tx * 4];
      const float4 bv1 = *(const float4*)&wvs[kk][tx * 4 + 64];
      FMA8(accm[0], a0, bm0, bm1)
      FMA8(accm[1], a1, bm0, bm1)
      FMA8(accv[0], a0, bv0, bv1)
      FMA8(accv[1], a1, bv0, bv1)
    }
    __syncthreads();
  }
  float bmv[8], bvv[8];
#pragma unroll
  for (int j = 0; j < 4; j++) {
    bmv[j] = bm[tx * 4 + j];      bmv[4 + j] = bm[tx * 4 + 64 + j];
    bvv[j] = bv[tx * 4 + j];      bvv[4 + j] = bv[tx * 4 + 64 + j];
  }
#pragma unroll
  for (int rr = 0; rr < 2; rr++) {
    const int i = row0 + ty * 2 + rr;
    const float n1 = norm1[i], n2 = norm2[i];
    float om[8], ov[8];
#pragma unroll
    for (int j = 0; j < 8; j++) {
      const float mean = fmaxf(accm[rr][j] + bmv[j], 0.f);
      const float var  = fmaxf(accv[rr][j] + bvv[j], 0.f);
      const float att = expf(-var);          // gamma = 1
      om[j] = mean * att * n1;
      ov[j] = var * att * att * n2;
    }
    *(uint4*)(mv16 + (size_t)i * 128 + tx * 4) =
        make_uint4(pack2(om[0], om[1]), pack2(ov[0], ov[1]),
                   pack2(om[2], om[3]), pack2(ov[2], ov[3]));
    *(uint4*)(mv16 + (size_t)i * 128 + 64 + tx * 4) =
        make_uint4(pack2(om[4], om[5]), pack2(ov[4], ov[5]),
                   pack2(om[6], om[7]), pack2(ov[6], ov[7]));
  }
}

// ---------------- layer-1 aggregation (no LDS, 1 wave per node) ----------------
// hmv layout: per node i, 256 floats: position k*2 = h_m(k), k*2+1 = h_v(k)
__global__ __launch_bounds__(256) void agg1_kernel(
    const int* __restrict__ row_ptr, const int* __restrict__ csr,
    const uint2* __restrict__ mv16,
    const float* __restrict__ norm1, const float* __restrict__ norm2,
    float* __restrict__ hmv) {
  const int wave = threadIdx.x >> 6, lane = threadIdx.x & 63;
  const int i = blockIdx.x * 4 + wave;
  const int e0 = row_ptr[i], e1 = row_ptr[i + 1];
  float amx = 0.f, amy = 0.f, avx = 0.f, avy = 0.f;
  int e = e0;
  for (; e + 2 <= e1; e += 2) {
    const uint2 q0 = mv16[(size_t)csr[e] * 64 + lane];
    const uint2 q1 = mv16[(size_t)csr[e + 1] * 64 + lane];
    amx += bflo(q0.x) + bflo(q1.x);
    amy += bfhi(q0.x) + bfhi(q1.x);
    avx += bflo(q0.y) + bflo(q1.y);
    avy += bfhi(q0.y) + bfhi(q1.y);
  }
  if (e < e1) {
    const uint2 q0 = mv16[(size_t)csr[e] * 64 + lane];
    amx += bflo(q0.x); amy += bfhi(q0.x);
    avx += bflo(q0.y); avy += bfhi(q0.y);
  }
  const float n1 = norm1[i], n2 = norm2[i];
  float4 o;
  o.x = fmaxf(amx * n1, 0.f);   // h_m(2l)
  o.y = fmaxf(avx * n2, 0.f);   // h_v(2l)
  o.z = fmaxf(amy * n1, 0.f);   // h_m(2l+1)
  o.w = fmaxf(avy * n2, 0.f);   // h_v(2l+1)
  *(float4*)&hmv[(size_t)i * 256 + lane * 4] = o;
}

// ---------------- layer 2 GEMM + epilogue -> packed bf16 messages ----------------
// m2v16 layout: per node i, 64 uints: uint[c] = bf16(m2_c) | bf16(v2_c)<<16
__global__ __launch_bounds__(256) void gemm2_kernel(
    const float* __restrict__ hmv,
    const float* __restrict__ wm2, const float* __restrict__ wv2,
    const float* __restrict__ bm2, const float* __restrict__ bv2,
    const float* __restrict__ norm1, const float* __restrict__ norm2,
    unsigned* __restrict__ m2v16) {
  __shared__ float wsh[2][64][64];   // 32 KB, K staged in 2 chunks
  const int t = threadIdx.x;
  const int r = t >> 3, c0 = (t & 7) << 3;
  const int i = blockIdx.x * 32 + r;
  const float* hrow = hmv + (size_t)i * 256;
  float accm[8] = {}, accv[8] = {};
  for (int kc = 0; kc < 2; kc++) {
#pragma unroll
    for (int ii = 0; ii < 4; ii++) {
      const int f4 = t + (ii << 8);     // 0..1023
      const int k = f4 >> 4, j4 = (f4 & 15) << 2;
      *(float4*)&wsh[0][k][j4] = *(const float4*)&wm2[(size_t)(kc * 64 + k) * 64 + j4];
      *(float4*)&wsh[1][k][j4] = *(const float4*)&wv2[(size_t)(kc * 64 + k) * 64 + j4];
    }
    __syncthreads();
#pragma unroll 8
    for (int kk = 0; kk < 64; kk++) {
      const float2 hh = *(const float2*)&hrow[(kc * 64 + kk) * 2];  // {h_m, h_v}
      const float4 b0 = *(const float4*)&wsh[0][kk][c0];
      const float4 b1 = *(const float4*)&wsh[0][kk][c0 + 4];
      const float4 d0 = *(const float4*)&wsh[1][kk][c0];
      const float4 d1 = *(const float4*)&wsh[1][kk][c0 + 4];
      FMA8(accm, hh.x, b0, b1)
      FMA8(accv, hh.y, d0, d1)
    }
    __syncthreads();
  }
  const float n1 = norm1[i], n2 = norm2[i];
  unsigned pk[8];
#pragma unroll
  for (int j = 0; j < 8; j++) {
    const float mean2 = fmaxf(accm[j] + bm2[c0 + j], 0.f);
    const float var2  = fmaxf(accv[j] + bv2[c0 + j], 0.f);
    const float att = expf(-var2);
    pk[j] = pack2(mean2 * att * n1, var2 * att * att * n2);
  }
  unsigned* dst = m2v16 + (size_t)i * 64 + c0;
  *(uint4*)(dst)     = make_uint4(pk[0], pk[1], pk[2], pk[3]);
  *(uint4*)(dst + 4) = make_uint4(pk[4], pk[5], pk[6], pk[7]);
}

// ---------------- layer-2 aggregation + reparameterization (fused) ----------------
// eps matches jax.random.normal(key(42)) with jax_threefry_partitionable=True:
// per element b, counter=(0,b), bits = o0 ^ o1.
__global__ __launch_bounds__(256) void agg2_reparam_kernel(
    const int* __restrict__ row_ptr, const int* __restrict__ csr,
    const unsigned* __restrict__ m2v16,
    const float* __restrict__ norm1, const float* __restrict__ norm2,
    float* __restrict__ out) {
  const int wave = threadIdx.x >> 6, lane = threadIdx.x & 63;
  const int i = blockIdx.x * 4 + wave;
  const int e0 = row_ptr[i], e1 = row_ptr[i + 1];
  float am = 0.f, av = 0.f;
  int e = e0;
  for (; e + 2 <= e1; e += 2) {
    const unsigned q0 = m2v16[(size_t)csr[e] * 64 + lane];
    const unsigned q1 = m2v16[(size_t)csr[e + 1] * 64 + lane];
    am += bflo(q0) + bflo(q1);
    av += bfhi(q0) + bfhi(q1);
  }
  if (e < e1) {
    const unsigned q0 = m2v16[(size_t)csr[e] * 64 + lane];
    am += bflo(q0); av += bfhi(q0);
  }
  const float mean = am * norm1[i];
  const float var  = av * norm2[i];
  const int b = i * 64 + lane;
  unsigned o0, o1;
  threefry2x32(0u, 42u, 0u, (unsigned)b, o0, o1);
  const float eps = bits_to_normal(o0 ^ o1);
  out[b] = eps * sqrtf(var + 1e-8f) + mean;
}

// ---------------- launch ----------------
extern "C" void kernel_launch(void* const* d_in, const int* in_sizes, int n_in,
                              void* d_out, int out_size, void* d_ws, size_t ws_size,
                              hipStream_t stream) {
  (void)in_sizes; (void)n_in; (void)out_size; (void)ws_size;
  const float* x   = (const float*)d_in[0];
  const int*   src = (const int*)d_in[1];
  const int*   dst = (const int*)d_in[2];
  const float* wm1 = (const float*)d_in[3];
  const float* wv1 = (const float*)d_in[4];
  const float* bm1 = (const float*)d_in[5];
  const float* bv1 = (const float*)d_in[6];
  const float* wm2 = (const float*)d_in[7];
  const float* wv2 = (const float*)d_in[8];
  const float* bm2 = (const float*)d_in[9];
  const float* bv2 = (const float*)d_in[10];
  float* out = (float*)d_out;

  char* base = (char*)d_ws;
  size_t off = 0;
  auto alloc = [&](size_t bytes) -> void* {
    void* p = base + off;
    off += (bytes + 255) & ~(size_t)255;
    return p;
  };
  int*      hist    = (int*)alloc((size_t)GN * 4);
  int*      row_ptr = (int*)alloc((size_t)(GN + 1) * 4);
  int*      fillc   = (int*)alloc((size_t)GN * 4);
  int*      csr     = (int*)alloc((size_t)GE * 4);
  float*    norm1   = (float*)alloc((size_t)GN * 4);
  float*    norm2   = (float*)alloc((size_t)GN * 4);
  unsigned* mv16    = (unsigned*)alloc((size_t)GN * 128 * 4);   // 51.2 MB (bf16-packed L1 messages)
  float*    hmv     = (float*)alloc((size_t)GN * 256 * 4);      // 102.4 MB (f32 interleaved h)
  unsigned* m2v16   = mv16;   // 25.6 MB needed; mv16 (51.2 MB) is dead after agg1

  hipMemsetAsync(hist, 0, (size_t)GN * 4, stream);
  hipMemsetAsync(fillc, 0, (size_t)GN * 4, stream);

  hist_kernel<<<(GE + 255) / 256, 256, 0, stream>>>(dst, hist);
  scan_kernel<<<1, 1024, 0, stream>>>(hist, row_ptr);
  norm_kernel<<<(GN + 255) / 256, 256, 0, stream>>>(hist, norm1, norm2);
  fill_kernel<<<(GE + 255) / 256, 256, 0, stream>>>(src, dst, row_ptr, fillc, csr);
  gemm1_kernel<<<GN / 32, 256, 0, stream>>>(x, wm1, wv1, bm1, bv1, norm1, norm2, mv16);
  agg1_kernel<<<GN / 4, 256, 0, stream>>>(row_ptr, csr, (const uint2*)mv16, norm1, norm2, hmv);
  gemm2_kernel<<<GN / 32, 256, 0, stream>>>(hmv, wm2, wv2, bm2, bv2, norm1, norm2, m2v16);
  agg2_reparam_kernel<<<GN / 4, 256, 0, stream>>>(row_ptr, csr, m2v16, norm1, norm2, out);
}

// Round 6
// 781.694 us; speedup vs baseline: 1.9339x; 1.0450x over previous
//
#include <hip/hip_runtime.h>

#define GN 100000
#define GE 1600000

// ---------------- bf16 pack/unpack ----------------
__device__ __forceinline__ unsigned bf16r(float f) {      // f32 -> bf16 bits (RNE)
  unsigned u = __float_as_uint(f);
  return (u + 0x7FFFu + ((u >> 16) & 1u)) >> 16;
}
__device__ __forceinline__ unsigned pack2(float lo, float hi) {
  return bf16r(lo) | (bf16r(hi) << 16);
}
__device__ __forceinline__ float bflo(unsigned u) { return __uint_as_float(u << 16); }
__device__ __forceinline__ float bfhi(unsigned u) { return __uint_as_float(u & 0xFFFF0000u); }

// ---------------- threefry2x32 (JAX-compatible) ----------------
__device__ __forceinline__ unsigned rotl32(unsigned x, int r) { return (x << r) | (x >> (32 - r)); }

__device__ __forceinline__ void threefry2x32(unsigned k0, unsigned k1,
                                             unsigned c0, unsigned c1,
                                             unsigned& o0, unsigned& o1) {
  const unsigned ks2 = k0 ^ k1 ^ 0x1BD11BDAu;
  unsigned x0 = c0 + k0, x1 = c1 + k1;
#define TF_R4(ra, rb, rc, rd) \
  x0 += x1; x1 = rotl32(x1, ra); x1 ^= x0; \
  x0 += x1; x1 = rotl32(x1, rb); x1 ^= x0; \
  x0 += x1; x1 = rotl32(x1, rc); x1 ^= x0; \
  x0 += x1; x1 = rotl32(x1, rd); x1 ^= x0;
  TF_R4(13, 15, 26, 6)  x0 += k1;  x1 += ks2 + 1u;
  TF_R4(17, 29, 16, 24) x0 += ks2; x1 += k0 + 2u;
  TF_R4(13, 15, 26, 6)  x0 += k0;  x1 += k1 + 3u;
  TF_R4(17, 29, 16, 24) x0 += k1;  x1 += ks2 + 4u;
  TF_R4(13, 15, 26, 6)  x0 += ks2; x1 += k0 + 5u;
#undef TF_R4
  o0 = x0; o1 = x1;
}

// uniform bits -> N(0,1) exactly as jax.random.normal (XLA erfinv polynomial)
__device__ __forceinline__ float bits_to_normal(unsigned bits) {
  const float lo = -0.99999994f;  // nextafter(-1, 0)
  const float u = __uint_as_float((bits >> 9) | 0x3f800000u) - 1.0f;  // [0,1)
  float x = u * 2.0f + lo;
  x = fmaxf(x, lo);
  float w = -log1pf(-x * x);
  float p;
  if (w < 5.0f) {
    w -= 2.5f;
    p = 2.81022636e-08f;
    p = fmaf(p, w, 3.43273939e-07f);
    p = fmaf(p, w, -3.5233877e-06f);
    p = fmaf(p, w, -4.39150654e-06f);
    p = fmaf(p, w, 0.00021858087f);
    p = fmaf(p, w, -0.00125372503f);
    p = fmaf(p, w, -0.00417768164f);
    p = fmaf(p, w, 0.246640727f);
    p = fmaf(p, w, 1.50140941f);
  } else {
    w = sqrtf(w) - 3.0f;
    p = -0.000200214257f;
    p = fmaf(p, w, 0.000100950558f);
    p = fmaf(p, w, 0.00134934322f);
    p = fmaf(p, w, -0.00367342844f);
    p = fmaf(p, w, 0.00573950773f);
    p = fmaf(p, w, -0.0076224613f);
    p = fmaf(p, w, 0.00943887047f);
    p = fmaf(p, w, 1.00167406f);
    p = fmaf(p, w, 2.83297682f);
  }
  return 1.41421356f * p * x;
}

// ---------------- CSR build ----------------
__global__ void hist_kernel(const int* __restrict__ dst, int* __restrict__ hist) {
  const int e = blockIdx.x * 256 + threadIdx.x;
  if (e < GE) atomicAdd(&hist[dst[e]], 1);
}

__global__ __launch_bounds__(1024) void scan_kernel(const int* __restrict__ hist,
                                                    int* __restrict__ row_ptr) {
  __shared__ int wsum[16];
  __shared__ int carry_s;
  const int t = threadIdx.x, lane = t & 63, wave = t >> 6;
  if (t == 0) carry_s = 0;
  __syncthreads();
  for (int base = 0; base < GN; base += 4096) {
    const int idx = base + t * 4;
    const int h0 = (idx + 0 < GN) ? hist[idx + 0] : 0;
    const int h1 = (idx + 1 < GN) ? hist[idx + 1] : 0;
    const int h2 = (idx + 2 < GN) ? hist[idx + 2] : 0;
    const int h3 = (idx + 3 < GN) ? hist[idx + 3] : 0;
    const int p0 = h0, p1 = h0 + h1, p2 = h0 + h1 + h2, p3 = h0 + h1 + h2 + h3;
    int s = p3;
#pragma unroll
    for (int o = 1; o < 64; o <<= 1) {
      const int u = __shfl_up(s, o, 64);
      if (lane >= o) s += u;
    }
    if (lane == 63) wsum[wave] = s;
    __syncthreads();
    int woff = 0;
    for (int w2 = 0; w2 < wave; w2++) woff += wsum[w2];
    const int carry = carry_s;
    __syncthreads();
    const int tb = carry + woff + (s - p3);  // exclusive base for this thread
    if (idx + 0 < GN) row_ptr[idx + 0] = tb;
    if (idx + 1 < GN) row_ptr[idx + 1] = tb + p0;
    if (idx + 2 < GN) row_ptr[idx + 2] = tb + p1;
    if (idx + 3 < GN) row_ptr[idx + 3] = tb + p2;
    if (t == 1023) carry_s = carry + woff + s;
    __syncthreads();
  }
  if (t == 0) row_ptr[GN] = carry_s;
}

__global__ void norm_kernel(const int* __restrict__ hist,
                            float* __restrict__ norm1, float* __restrict__ norm2) {
  const int i = blockIdx.x * 256 + threadIdx.x;
  if (i < GN) {
    const double d = (double)max(hist[i], 1);
    norm1[i] = (float)(1.0 / sqrt(d));
    norm2[i] = (float)(1.0 / d);
  }
}

__global__ void fill_kernel(const int* __restrict__ src, const int* __restrict__ dst,
                            const int* __restrict__ row_ptr, int* __restrict__ fillc,
                            int* __restrict__ csr) {
  const int e = blockIdx.x * 256 + threadIdx.x;
  if (e < GE) {
    const int d = dst[e];
    const int pos = atomicAdd(&fillc[d], 1);
    csr[row_ptr[d] + pos] = src[e];
  }
}

// ---------------- layer 1 GEMM (f32) + epilogue -> packed bf16 messages ----------------
// 64-row blocks, 4 rows x 8 cols per thread: 64 FMA per (4 b32 + 4 b128) LDS reads.
#define FMA8(acc, a, p0, p1)                                                        \
  acc[0] = fmaf(a, p0.x, acc[0]); acc[1] = fmaf(a, p0.y, acc[1]);                   \
  acc[2] = fmaf(a, p0.z, acc[2]); acc[3] = fmaf(a, p0.w, acc[3]);                   \
  acc[4] = fmaf(a, p1.x, acc[4]); acc[5] = fmaf(a, p1.y, acc[5]);                   \
  acc[6] = fmaf(a, p1.z, acc[6]); acc[7] = fmaf(a, p1.w, acc[7]);

__global__ __launch_bounds__(256) void gemm1_kernel(
    const float* __restrict__ x,
    const float* __restrict__ wm, const float* __restrict__ wv,
    const float* __restrict__ bm, const float* __restrict__ bv,
    const float* __restrict__ norm1, const float* __restrict__ norm2,
    unsigned* __restrict__ mv16) {
  __shared__ float xs[64][33];       // 8.4 KB
  __shared__ float wms[32][128];     // 16 KB
  __shared__ float wvs[32][128];     // 16 KB
  const int t = threadIdx.x;
  const int row0 = blockIdx.x * 64;
  const int ty = t >> 4, tx = t & 15;  // rows ty*4+{0..3}, cols {tx*4..+3, tx*4+64..+67}
  float accm[4][8] = {};
  float accv[4][8] = {};
  for (int k0 = 0; k0 < 256; k0 += 32) {
#pragma unroll
    for (int i = 0; i < 2; i++) {
      const int f = t + (i << 8);           // 0..511
      const int r = f >> 3, c4 = (f & 7) << 2;
      const int rg = min(row0 + r, GN - 1); // guard last block
      *(float4*)&xs[r][c4] = *(const float4*)&x[(size_t)rg * 256 + k0 + c4];
    }
#pragma unroll
    for (int i = 0; i < 4; i++) {
      const int f = t + (i << 8);           // float4 index 0..1023
      const int kk = f >> 5, j4 = (f & 31) << 2;
      *(float4*)&wms[kk][j4] = *(const float4*)&wm[(size_t)(k0 + kk) * 128 + j4];
      *(float4*)&wvs[kk][j4] = *(const float4*)&wv[(size_t)(k0 + kk) * 128 + j4];
    }
    __syncthreads();
#pragma unroll 4
    for (int kk = 0; kk < 32; kk++) {
      const float4 bm0 = *(const float4*)&wms[kk][tx * 4];
      const float4 bm1 = *(const float4*)&wms[kk][tx * 4 + 64];
      const float4 bv0 = *(const float4*)&wvs[kk][tx * 4];
      const float4 bv1 = *(const float4*)&wvs[kk][tx * 4 + 64];
#pragma unroll
      for (int r = 0; r < 4; r++) {
        const float a = xs[ty * 4 + r][kk];
        FMA8(accm[r], a, bm0, bm1)
        FMA8(accv[r], a, bv0, bv1)
      }
    }
    __syncthreads();
  }
  float bmv[8], bvv[8];
#pragma unroll
  for (int j = 0; j < 4; j++) {
    bmv[j] = bm[tx * 4 + j];      bmv[4 + j] = bm[tx * 4 + 64 + j];
    bvv[j] = bv[tx * 4 + j];      bvv[4 + j] = bv[tx * 4 + 64 + j];
  }
#pragma unroll
  for (int rr = 0; rr < 4; rr++) {
    const int i = row0 + ty * 4 + rr;
    if (i >= GN) break;
    const float n1 = norm1[i], n2 = norm2[i];
    float om[8], ov[8];
#pragma unroll
    for (int j = 0; j < 8; j++) {
      const float mean = fmaxf(accm[rr][j] + bmv[j], 0.f);
      const float var  = fmaxf(accv[rr][j] + bvv[j], 0.f);
      const float att = expf(-var);          // gamma = 1
      om[j] = mean * att * n1;
      ov[j] = var * att * att * n2;
    }
    *(uint4*)(mv16 + (size_t)i * 128 + tx * 4) =
        make_uint4(pack2(om[0], om[1]), pack2(ov[0], ov[1]),
                   pack2(om[2], om[3]), pack2(ov[2], ov[3]));
    *(uint4*)(mv16 + (size_t)i * 128 + 64 + tx * 4) =
        make_uint4(pack2(om[4], om[5]), pack2(ov[4], ov[5]),
                   pack2(om[6], om[7]), pack2(ov[6], ov[7]));
  }
}

// ---------------- layer-1 aggregation (no LDS, 1 wave per node, 4-edge unroll) ----------------
__global__ __launch_bounds__(256) void agg1_kernel(
    const int* __restrict__ row_ptr, const int* __restrict__ csr,
    const uint2* __restrict__ mv16,
    const float* __restrict__ norm1, const float* __restrict__ norm2,
    float* __restrict__ hmv) {
  const int wave = threadIdx.x >> 6, lane = threadIdx.x & 63;
  const int i = blockIdx.x * 4 + wave;
  const int e0 = row_ptr[i], e1 = row_ptr[i + 1];
  float amx0 = 0.f, amy0 = 0.f, avx0 = 0.f, avy0 = 0.f;
  float amx1 = 0.f, amy1 = 0.f, avx1 = 0.f, avy1 = 0.f;
  int e = e0;
  for (; e + 4 <= e1; e += 4) {
    const int s0 = csr[e], s1 = csr[e + 1], s2 = csr[e + 2], s3 = csr[e + 3];
    const uint2 q0 = mv16[(size_t)s0 * 64 + lane];
    const uint2 q1 = mv16[(size_t)s1 * 64 + lane];
    const uint2 q2 = mv16[(size_t)s2 * 64 + lane];
    const uint2 q3 = mv16[(size_t)s3 * 64 + lane];
    amx0 += bflo(q0.x) + bflo(q1.x); amx1 += bflo(q2.x) + bflo(q3.x);
    amy0 += bfhi(q0.x) + bfhi(q1.x); amy1 += bfhi(q2.x) + bfhi(q3.x);
    avx0 += bflo(q0.y) + bflo(q1.y); avx1 += bflo(q2.y) + bflo(q3.y);
    avy0 += bfhi(q0.y) + bfhi(q1.y); avy1 += bfhi(q2.y) + bfhi(q3.y);
  }
  for (; e < e1; e++) {
    const uint2 q0 = mv16[(size_t)csr[e] * 64 + lane];
    amx0 += bflo(q0.x); amy0 += bfhi(q0.x);
    avx0 += bflo(q0.y); avy0 += bfhi(q0.y);
  }
  const float amx = amx0 + amx1, amy = amy0 + amy1;
  const float avx = avx0 + avx1, avy = avy0 + avy1;
  const float n1 = norm1[i], n2 = norm2[i];
  float4 o;
  o.x = fmaxf(amx * n1, 0.f);   // h_m(2l)
  o.y = fmaxf(avx * n2, 0.f);   // h_v(2l)
  o.z = fmaxf(amy * n1, 0.f);   // h_m(2l+1)
  o.w = fmaxf(avy * n2, 0.f);   // h_v(2l+1)
  *(float4*)&hmv[(size_t)i * 256 + lane * 4] = o;
}

// ---------------- layer 2 GEMM + epilogue -> packed bf16 messages ----------------
// m2v16 layout: per node i, 64 uints: uint[c] = bf16(m2_c) | bf16(v2_c)<<16
__global__ __launch_bounds__(256) void gemm2_kernel(
    const float* __restrict__ hmv,
    const float* __restrict__ wm2, const float* __restrict__ wv2,
    const float* __restrict__ bm2, const float* __restrict__ bv2,
    const float* __restrict__ norm1, const float* __restrict__ norm2,
    unsigned* __restrict__ m2v16) {
  __shared__ float wsh[2][64][64];   // 32 KB, K staged in 2 chunks
  const int t = threadIdx.x;
  const int r = t >> 3, c0 = (t & 7) << 3;
  const int i = blockIdx.x * 32 + r;
  const float* hrow = hmv + (size_t)i * 256;
  float accm[8] = {}, accv[8] = {};
  for (int kc = 0; kc < 2; kc++) {
#pragma unroll
    for (int ii = 0; ii < 4; ii++) {
      const int f4 = t + (ii << 8);     // 0..1023
      const int k = f4 >> 4, j4 = (f4 & 15) << 2;
      *(float4*)&wsh[0][k][j4] = *(const float4*)&wm2[(size_t)(kc * 64 + k) * 64 + j4];
      *(float4*)&wsh[1][k][j4] = *(const float4*)&wv2[(size_t)(kc * 64 + k) * 64 + j4];
    }
    __syncthreads();
#pragma unroll 8
    for (int kk = 0; kk < 64; kk++) {
      const float2 hh = *(const float2*)&hrow[(kc * 64 + kk) * 2];  // {h_m, h_v}
      const float4 b0 = *(const float4*)&wsh[0][kk][c0];
      const float4 b1 = *(const float4*)&wsh[0][kk][c0 + 4];
      const float4 d0 = *(const float4*)&wsh[1][kk][c0];
      const float4 d1 = *(const float4*)&wsh[1][kk][c0 + 4];
      FMA8(accm, hh.x, b0, b1)
      FMA8(accv, hh.y, d0, d1)
    }
    __syncthreads();
  }
  const float n1 = norm1[i], n2 = norm2[i];
  unsigned pk[8];
#pragma unroll
  for (int j = 0; j < 8; j++) {
    const float mean2 = fmaxf(accm[j] + bm2[c0 + j], 0.f);
    const float var2  = fmaxf(accv[j] + bv2[c0 + j], 0.f);
    const float att = expf(-var2);
    pk[j] = pack2(mean2 * att * n1, var2 * att * att * n2);
  }
  unsigned* dstp = m2v16 + (size_t)i * 64 + c0;
  *(uint4*)(dstp)     = make_uint4(pk[0], pk[1], pk[2], pk[3]);
  *(uint4*)(dstp + 4) = make_uint4(pk[4], pk[5], pk[6], pk[7]);
}

// ---------------- layer-2 aggregation + reparameterization (fused, 4-edge unroll) ----------------
// eps matches jax.random.normal(key(42)) with jax_threefry_partitionable=True:
// per element b, counter=(0,b), bits = o0 ^ o1.
__global__ __launch_bounds__(256) void agg2_reparam_kernel(
    const int* __restrict__ row_ptr, const int* __restrict__ csr,
    const unsigned* __restrict__ m2v16,
    const float* __restrict__ norm1, const float* __restrict__ norm2,
    float* __restrict__ out) {
  const int wave = threadIdx.x >> 6, lane = threadIdx.x & 63;
  const int i = blockIdx.x * 4 + wave;
  const int e0 = row_ptr[i], e1 = row_ptr[i + 1];
  float am0 = 0.f, av0 = 0.f, am1 = 0.f, av1 = 0.f;
  int e = e0;
  for (; e + 4 <= e1; e += 4) {
    const int s0 = csr[e], s1 = csr[e + 1], s2 = csr[e + 2], s3 = csr[e + 3];
    const unsigned q0 = m2v16[(size_t)s0 * 64 + lane];
    const unsigned q1 = m2v16[(size_t)s1 * 64 + lane];
    const unsigned q2 = m2v16[(size_t)s2 * 64 + lane];
    const unsigned q3 = m2v16[(size_t)s3 * 64 + lane];
    am0 += bflo(q0) + bflo(q1); am1 += bflo(q2) + bflo(q3);
    av0 += bfhi(q0) + bfhi(q1); av1 += bfhi(q2) + bfhi(q3);
  }
  for (; e < e1; e++) {
    const unsigned q0 = m2v16[(size_t)csr[e] * 64 + lane];
    am0 += bflo(q0); av0 += bfhi(q0);
  }
  const float mean = (am0 + am1) * norm1[i];
  const float var  = (av0 + av1) * norm2[i];
  const int b = i * 64 + lane;
  unsigned o0, o1;
  threefry2x32(0u, 42u, 0u, (unsigned)b, o0, o1);
  const float eps = bits_to_normal(o0 ^ o1);
  out[b] = eps * sqrtf(var + 1e-8f) + mean;
}

// ---------------- launch ----------------
extern "C" void kernel_launch(void* const* d_in, const int* in_sizes, int n_in,
                              void* d_out, int out_size, void* d_ws, size_t ws_size,
                              hipStream_t stream) {
  (void)in_sizes; (void)n_in; (void)out_size; (void)ws_size;
  const float* x   = (const float*)d_in[0];
  const int*   src = (const int*)d_in[1];
  const int*   dst = (const int*)d_in[2];
  const float* wm1 = (const float*)d_in[3];
  const float* wv1 = (const float*)d_in[4];
  const float* bm1 = (const float*)d_in[5];
  const float* bv1 = (const float*)d_in[6];
  const float* wm2 = (const float*)d_in[7];
  const float* wv2 = (const float*)d_in[8];
  const float* bm2 = (const float*)d_in[9];
  const float* bv2 = (const float*)d_in[10];
  float* out = (float*)d_out;

  char* base = (char*)d_ws;
  size_t off = 0;
  auto alloc = [&](size_t bytes) -> void* {
    void* p = base + off;
    off += (bytes + 255) & ~(size_t)255;
    return p;
  };
  int*      hist    = (int*)alloc((size_t)GN * 4);
  int*      row_ptr = (int*)alloc((size_t)(GN + 1) * 4);
  int*      fillc   = (int*)alloc((size_t)GN * 4);
  int*      csr     = (int*)alloc((size_t)GE * 4);
  float*    norm1   = (float*)alloc((size_t)GN * 4);
  float*    norm2   = (float*)alloc((size_t)GN * 4);
  unsigned* mv16    = (unsigned*)alloc((size_t)GN * 128 * 4);   // 51.2 MB (bf16-packed L1 messages)
  float*    hmv     = (float*)alloc((size_t)GN * 256 * 4);      // 102.4 MB (f32 interleaved h)
  unsigned* m2v16   = mv16;   // 25.6 MB needed; mv16 (51.2 MB) is dead after agg1

  hipMemsetAsync(hist, 0, (size_t)GN * 4, stream);
  hipMemsetAsync(fillc, 0, (size_t)GN * 4, stream);

  hist_kernel<<<(GE + 255) / 256, 256, 0, stream>>>(dst, hist);
  scan_kernel<<<1, 1024, 0, stream>>>(hist, row_ptr);
  norm_kernel<<<(GN + 255) / 256, 256, 0, stream>>>(hist, norm1, norm2);
  fill_kernel<<<(GE + 255) / 256, 256, 0, stream>>>(src, dst, row_ptr, fillc, csr);
  gemm1_kernel<<<(GN + 63) / 64, 256, 0, stream>>>(x, wm1, wv1, bm1, bv1, norm1, norm2, mv16);
  agg1_kernel<<<GN / 4, 256, 0, stream>>>(row_ptr, csr, (const uint2*)mv16, norm1, norm2, hmv);
  gemm2_kernel<<<GN / 32, 256, 0, stream>>>(hmv, wm2, wv2, bm2, bv2, norm1, norm2, m2v16);
  agg2_reparam_kernel<<<GN / 4, 256, 0, stream>>>(row_ptr, csr, m2v16, norm1, norm2, out);
}

// Round 7
// 658.617 us; speedup vs baseline: 2.2952x; 1.1869x over previous
//
#include <hip/hip_runtime.h>

#define GN 100000
#define GE 1600000
#define NT1 6250      // GN/16 row-tiles

typedef _Float16 f16;
typedef f16 f16x8 __attribute__((ext_vector_type(8)));
typedef float f32x4 __attribute__((ext_vector_type(4)));

// ---------------- bf16 pack/unpack ----------------
__device__ __forceinline__ unsigned bf16r(float f) {      // f32 -> bf16 bits (RNE)
  unsigned u = __float_as_uint(f);
  return (u + 0x7FFFu + ((u >> 16) & 1u)) >> 16;
}
__device__ __forceinline__ unsigned pack2(float lo, float hi) {
  return bf16r(lo) | (bf16r(hi) << 16);
}
__device__ __forceinline__ float bflo(unsigned u) { return __uint_as_float(u << 16); }
__device__ __forceinline__ float bfhi(unsigned u) { return __uint_as_float(u & 0xFFFF0000u); }

__device__ __forceinline__ unsigned packf16(float a, float b) {
  const unsigned ua = (unsigned)__builtin_bit_cast(unsigned short, (f16)a);
  const unsigned ub = (unsigned)__builtin_bit_cast(unsigned short, (f16)b);
  return ua | (ub << 16);
}

// ---------------- threefry2x32 (JAX-compatible) ----------------
__device__ __forceinline__ unsigned rotl32(unsigned x, int r) { return (x << r) | (x >> (32 - r)); }

__device__ __forceinline__ void threefry2x32(unsigned k0, unsigned k1,
                                             unsigned c0, unsigned c1,
                                             unsigned& o0, unsigned& o1) {
  const unsigned ks2 = k0 ^ k1 ^ 0x1BD11BDAu;
  unsigned x0 = c0 + k0, x1 = c1 + k1;
#define TF_R4(ra, rb, rc, rd) \
  x0 += x1; x1 = rotl32(x1, ra); x1 ^= x0; \
  x0 += x1; x1 = rotl32(x1, rb); x1 ^= x0; \
  x0 += x1; x1 = rotl32(x1, rc); x1 ^= x0; \
  x0 += x1; x1 = rotl32(x1, rd); x1 ^= x0;
  TF_R4(13, 15, 26, 6)  x0 += k1;  x1 += ks2 + 1u;
  TF_R4(17, 29, 16, 24) x0 += ks2; x1 += k0 + 2u;
  TF_R4(13, 15, 26, 6)  x0 += k0;  x1 += k1 + 3u;
  TF_R4(17, 29, 16, 24) x0 += k1;  x1 += ks2 + 4u;
  TF_R4(13, 15, 26, 6)  x0 += ks2; x1 += k0 + 5u;
#undef TF_R4
  o0 = x0; o1 = x1;
}

// uniform bits -> N(0,1) exactly as jax.random.normal (XLA erfinv polynomial)
__device__ __forceinline__ float bits_to_normal(unsigned bits) {
  const float lo = -0.99999994f;  // nextafter(-1, 0)
  const float u = __uint_as_float((bits >> 9) | 0x3f800000u) - 1.0f;  // [0,1)
  float x = u * 2.0f + lo;
  x = fmaxf(x, lo);
  float w = -log1pf(-x * x);
  float p;
  if (w < 5.0f) {
    w -= 2.5f;
    p = 2.81022636e-08f;
    p = fmaf(p, w, 3.43273939e-07f);
    p = fmaf(p, w, -3.5233877e-06f);
    p = fmaf(p, w, -4.39150654e-06f);
    p = fmaf(p, w, 0.00021858087f);
    p = fmaf(p, w, -0.00125372503f);
    p = fmaf(p, w, -0.00417768164f);
    p = fmaf(p, w, 0.246640727f);
    p = fmaf(p, w, 1.50140941f);
  } else {
    w = sqrtf(w) - 3.0f;
    p = -0.000200214257f;
    p = fmaf(p, w, 0.000100950558f);
    p = fmaf(p, w, 0.00134934322f);
    p = fmaf(p, w, -0.00367342844f);
    p = fmaf(p, w, 0.00573950773f);
    p = fmaf(p, w, -0.0076224613f);
    p = fmaf(p, w, 0.00943887047f);
    p = fmaf(p, w, 1.00167406f);
    p = fmaf(p, w, 2.83297682f);
  }
  return 1.41421356f * p * x;
}

// ---------------- CSR build ----------------
__global__ void hist_kernel(const int* __restrict__ dst, int* __restrict__ hist) {
  const int e = blockIdx.x * 256 + threadIdx.x;
  if (e < GE) atomicAdd(&hist[dst[e]], 1);
}

__global__ __launch_bounds__(1024) void scan_kernel(const int* __restrict__ hist,
                                                    int* __restrict__ row_ptr) {
  __shared__ int wsum[16];
  __shared__ int carry_s;
  const int t = threadIdx.x, lane = t & 63, wave = t >> 6;
  if (t == 0) carry_s = 0;
  __syncthreads();
  for (int base = 0; base < GN; base += 4096) {
    const int idx = base + t * 4;
    const int h0 = (idx + 0 < GN) ? hist[idx + 0] : 0;
    const int h1 = (idx + 1 < GN) ? hist[idx + 1] : 0;
    const int h2 = (idx + 2 < GN) ? hist[idx + 2] : 0;
    const int h3 = (idx + 3 < GN) ? hist[idx + 3] : 0;
    const int p0 = h0, p1 = h0 + h1, p2 = h0 + h1 + h2, p3 = h0 + h1 + h2 + h3;
    int s = p3;
#pragma unroll
    for (int o = 1; o < 64; o <<= 1) {
      const int u = __shfl_up(s, o, 64);
      if (lane >= o) s += u;
    }
    if (lane == 63) wsum[wave] = s;
    __syncthreads();
    int woff = 0;
    for (int w2 = 0; w2 < wave; w2++) woff += wsum[w2];
    const int carry = carry_s;
    __syncthreads();
    const int tb = carry + woff + (s - p3);  // exclusive base for this thread
    if (idx + 0 < GN) row_ptr[idx + 0] = tb;
    if (idx + 1 < GN) row_ptr[idx + 1] = tb + p0;
    if (idx + 2 < GN) row_ptr[idx + 2] = tb + p1;
    if (idx + 3 < GN) row_ptr[idx + 3] = tb + p2;
    if (t == 1023) carry_s = carry + woff + s;
    __syncthreads();
  }
  if (t == 0) row_ptr[GN] = carry_s;
}

__global__ void norm_kernel(const int* __restrict__ hist,
                            float* __restrict__ norm1, float* __restrict__ norm2) {
  const int i = blockIdx.x * 256 + threadIdx.x;
  if (i < GN) {
    const double d = (double)max(hist[i], 1);
    norm1[i] = (float)(1.0 / sqrt(d));
    norm2[i] = (float)(1.0 / d);
  }
}

__global__ void fill_kernel(const int* __restrict__ src, const int* __restrict__ dst,
                            const int* __restrict__ row_ptr, int* __restrict__ fillc,
                            int* __restrict__ csr) {
  const int e = blockIdx.x * 256 + threadIdx.x;
  if (e < GE) {
    const int d = dst[e];
    const int pos = atomicAdd(&fillc[d], 1);
    csr[row_ptr[d] + pos] = src[e];
  }
}

// ---------------- weight pre-pack to f16 MFMA fragment order ----------------
// packed[((kt*NT + nt)*64 + l)*8 + j] = (f16) W[kt*32 + (l>>4)*8 + j][nt*16 + (l&15)]
__global__ __launch_bounds__(64) void pack_w_kernel(
    const float* __restrict__ w1m, const float* __restrict__ w1v,
    const float* __restrict__ w2m, const float* __restrict__ w2v,
    f16* __restrict__ p1m, f16* __restrict__ p1v,
    f16* __restrict__ p2m, f16* __restrict__ p2v) {
  const int b = blockIdx.x, l = threadIdx.x;
  const float* srcw; f16* dstw; int kt, nt, N;
  if (b < 64)       { srcw = w1m; dstw = p1m; kt = b >> 3;         nt = b & 7;         N = 128; }
  else if (b < 128) { srcw = w1v; dstw = p1v; kt = (b - 64) >> 3;  nt = (b - 64) & 7;  N = 128; }
  else if (b < 144) { srcw = w2m; dstw = p2m; kt = (b - 128) >> 2; nt = (b - 128) & 3; N = 64; }
  else              { srcw = w2v; dstw = p2v; kt = (b - 144) >> 2; nt = (b - 144) & 3; N = 64; }
  const int NTn = N >> 4;
  f16* out = dstw + ((size_t)(kt * NTn + nt) * 64 + l) * 8;
  const int k0 = kt * 32 + (l >> 4) * 8;
  const int c  = nt * 16 + (l & 15);
#pragma unroll
  for (int j = 0; j < 8; j++) out[j] = (f16)srcw[(size_t)(k0 + j) * N + c];
}

// ---------------- layer 1 GEMM: f16 MFMA + epilogue -> packed bf16 messages ----------------
// mv16 layout: per node i, 128 uints: uint[f] = bf16(m_f) | bf16(v_f)<<16
__global__ __launch_bounds__(256) void gemm1_kernel(
    const float* __restrict__ x,
    const f16x8* __restrict__ p1m, const f16x8* __restrict__ p1v,
    const float* __restrict__ bm, const float* __restrict__ bv,
    const float* __restrict__ norm1, const float* __restrict__ norm2,
    unsigned* __restrict__ mv16) {
  __shared__ unsigned ep[4][16][132];   // 33.8 KB, wave-private [wv] slices
  const int wv = threadIdx.x >> 6, l = threadIdx.x & 63;
  const int rt = blockIdx.x * 4 + wv;
  if (rt >= NT1) return;                 // no __syncthreads below (wave-local LDS only)
  const int r0 = rt * 16;
  const int lm = l & 15, lk = l >> 4;
  f32x4 accm[8], accv[8];
#pragma unroll
  for (int nt = 0; nt < 8; nt++) {
    accm[nt] = (f32x4){0.f, 0.f, 0.f, 0.f};
    accv[nt] = (f32x4){0.f, 0.f, 0.f, 0.f};
  }
  const float* xrow = x + (size_t)(r0 + lm) * 256 + lk * 8;
  for (int kt = 0; kt < 8; kt++) {
    const float4 xlo = *(const float4*)(xrow + kt * 32);
    const float4 xhi = *(const float4*)(xrow + kt * 32 + 4);
    f16x8 a;
    a[0] = (f16)xlo.x; a[1] = (f16)xlo.y; a[2] = (f16)xlo.z; a[3] = (f16)xlo.w;
    a[4] = (f16)xhi.x; a[5] = (f16)xhi.y; a[6] = (f16)xhi.z; a[7] = (f16)xhi.w;
#pragma unroll
    for (int nt = 0; nt < 8; nt++) {
      const f16x8 bmf = p1m[(kt * 8 + nt) * 64 + l];
      const f16x8 bvf = p1v[(kt * 8 + nt) * 64 + l];
      accm[nt] = __builtin_amdgcn_mfma_f32_16x16x32_f16(a, bmf, accm[nt], 0, 0, 0);
      accv[nt] = __builtin_amdgcn_mfma_f32_16x16x32_f16(a, bvf, accv[nt], 0, 0, 0);
    }
  }
  // epilogue: C[row=(lk*4+r)][col=nt*16+lm]; bias/relu/att/scale, pack {m,v}, LDS transpose
  float n1r[4], n2r[4];
#pragma unroll
  for (int r = 0; r < 4; r++) {
    n1r[r] = norm1[r0 + lk * 4 + r];
    n2r[r] = norm2[r0 + lk * 4 + r];
  }
#pragma unroll
  for (int nt = 0; nt < 8; nt++) {
    const float bmc = bm[nt * 16 + lm];
    const float bvc = bv[nt * 16 + lm];
#pragma unroll
    for (int r = 0; r < 4; r++) {
      const float mean = fmaxf(accm[nt][r] + bmc, 0.f);
      const float var  = fmaxf(accv[nt][r] + bvc, 0.f);
      const float att = expf(-var);          // gamma = 1
      ep[wv][lk * 4 + r][nt * 16 + lm] = pack2(mean * att * n1r[r], var * att * att * n2r[r]);
    }
  }
  asm volatile("s_waitcnt lgkmcnt(0)" ::: "memory");   // wave-local LDS RAW fence
  unsigned* dstp = mv16 + (size_t)(r0 + lm) * 128 + lk * 32;
#pragma unroll
  for (int k2 = 0; k2 < 8; k2++)
    *(uint4*)(dstp + k2 * 4) = *(uint4*)&ep[wv][lm][lk * 32 + k2 * 4];
}

// ---------------- layer-1 aggregation (no LDS, 1 wave/node, 4-edge unroll) ----------------
// output: hm/hv[node][64 u32], u32[l] = f16(h(2l)) | f16(h(2l+1))<<16  (row-major f16[128])
__global__ __launch_bounds__(256) void agg1_kernel(
    const int* __restrict__ row_ptr, const int* __restrict__ csr,
    const uint2* __restrict__ mv16,
    const float* __restrict__ norm1, const float* __restrict__ norm2,
    unsigned* __restrict__ hm, unsigned* __restrict__ hv) {
  const int wave = threadIdx.x >> 6, lane = threadIdx.x & 63;
  const int i = blockIdx.x * 4 + wave;
  const int e0 = row_ptr[i], e1 = row_ptr[i + 1];
  float m0a = 0.f, m0b = 0.f, m1a = 0.f, m1b = 0.f;
  float v0a = 0.f, v0b = 0.f, v1a = 0.f, v1b = 0.f;
  int e = e0;
  for (; e + 4 <= e1; e += 4) {
    const int s0 = csr[e], s1 = csr[e + 1], s2 = csr[e + 2], s3 = csr[e + 3];
    const uint2 q0 = mv16[(size_t)s0 * 64 + lane];
    const uint2 q1 = mv16[(size_t)s1 * 64 + lane];
    const uint2 q2 = mv16[(size_t)s2 * 64 + lane];
    const uint2 q3 = mv16[(size_t)s3 * 64 + lane];
    m0a += bflo(q0.x) + bflo(q1.x); m0b += bflo(q2.x) + bflo(q3.x);
    v0a += bfhi(q0.x) + bfhi(q1.x); v0b += bfhi(q2.x) + bfhi(q3.x);
    m1a += bflo(q0.y) + bflo(q1.y); m1b += bflo(q2.y) + bflo(q3.y);
    v1a += bfhi(q0.y) + bfhi(q1.y); v1b += bfhi(q2.y) + bfhi(q3.y);
  }
  for (; e < e1; e++) {
    const uint2 q0 = mv16[(size_t)csr[e] * 64 + lane];
    m0a += bflo(q0.x); v0a += bfhi(q0.x);
    m1a += bflo(q0.y); v1a += bfhi(q0.y);
  }
  const float n1 = norm1[i], n2 = norm2[i];
  const float h_m0 = fmaxf((m0a + m0b) * n1, 0.f);
  const float h_m1 = fmaxf((m1a + m1b) * n1, 0.f);
  const float h_v0 = fmaxf((v0a + v0b) * n2, 0.f);
  const float h_v1 = fmaxf((v1a + v1b) * n2, 0.f);
  hm[(size_t)i * 64 + lane] = packf16(h_m0, h_m1);
  hv[(size_t)i * 64 + lane] = packf16(h_v0, h_v1);
}

// ---------------- layer 2 GEMM: f16 MFMA + epilogue -> packed bf16 messages ----------------
// m2v16 layout: per node i, 64 uints: uint[c] = bf16(m2_c) | bf16(v2_c)<<16
__global__ __launch_bounds__(256) void gemm2_kernel(
    const unsigned* __restrict__ hm, const unsigned* __restrict__ hv,
    const f16x8* __restrict__ p2m, const f16x8* __restrict__ p2v,
    const float* __restrict__ bm2, const float* __restrict__ bv2,
    const float* __restrict__ norm1, const float* __restrict__ norm2,
    unsigned* __restrict__ m2v16) {
  __shared__ unsigned ep[4][16][68];    // 17.4 KB, wave-private
  const int wv = threadIdx.x >> 6, l = threadIdx.x & 63;
  const int rt = blockIdx.x * 4 + wv;
  if (rt >= NT1) return;
  const int r0 = rt * 16;
  const int lm = l & 15, lk = l >> 4;
  f32x4 accm[4], accv[4];
#pragma unroll
  for (int nt = 0; nt < 4; nt++) {
    accm[nt] = (f32x4){0.f, 0.f, 0.f, 0.f};
    accv[nt] = (f32x4){0.f, 0.f, 0.f, 0.f};
  }
  const f16x8* hmrow = (const f16x8*)(hm + (size_t)(r0 + lm) * 64);
  const f16x8* hvrow = (const f16x8*)(hv + (size_t)(r0 + lm) * 64);
  for (int kt = 0; kt < 4; kt++) {
    const f16x8 am = hmrow[kt * 4 + lk];
    const f16x8 av = hvrow[kt * 4 + lk];
#pragma unroll
    for (int nt = 0; nt < 4; nt++) {
      const f16x8 bmf = p2m[(kt * 4 + nt) * 64 + l];
      const f16x8 bvf = p2v[(kt * 4 + nt) * 64 + l];
      accm[nt] = __builtin_amdgcn_mfma_f32_16x16x32_f16(am, bmf, accm[nt], 0, 0, 0);
      accv[nt] = __builtin_amdgcn_mfma_f32_16x16x32_f16(av, bvf, accv[nt], 0, 0, 0);
    }
  }
  float n1r[4], n2r[4];
#pragma unroll
  for (int r = 0; r < 4; r++) {
    n1r[r] = norm1[r0 + lk * 4 + r];
    n2r[r] = norm2[r0 + lk * 4 + r];
  }
#pragma unroll
  for (int nt = 0; nt < 4; nt++) {
    const float bmc = bm2[nt * 16 + lm];
    const float bvc = bv2[nt * 16 + lm];
#pragma unroll
    for (int r = 0; r < 4; r++) {
      const float mean2 = fmaxf(accm[nt][r] + bmc, 0.f);
      const float var2  = fmaxf(accv[nt][r] + bvc, 0.f);
      const float att = expf(-var2);
      ep[wv][lk * 4 + r][nt * 16 + lm] = pack2(mean2 * att * n1r[r], var2 * att * att * n2r[r]);
    }
  }
  asm volatile("s_waitcnt lgkmcnt(0)" ::: "memory");
  unsigned* dstp = m2v16 + (size_t)(r0 + lm) * 64 + lk * 16;
#pragma unroll
  for (int k2 = 0; k2 < 4; k2++)
    *(uint4*)(dstp + k2 * 4) = *(uint4*)&ep[wv][lm][lk * 16 + k2 * 4];
}

// ---------------- layer-2 aggregation + reparameterization (fused, 4-edge unroll) ----------------
// eps matches jax.random.normal(key(42)) with jax_threefry_partitionable=True:
// per element b, counter=(0,b), bits = o0 ^ o1.
__global__ __launch_bounds__(256) void agg2_reparam_kernel(
    const int* __restrict__ row_ptr, const int* __restrict__ csr,
    const unsigned* __restrict__ m2v16,
    const float* __restrict__ norm1, const float* __restrict__ norm2,
    float* __restrict__ out) {
  const int wave = threadIdx.x >> 6, lane = threadIdx.x & 63;
  const int i = blockIdx.x * 4 + wave;
  const int e0 = row_ptr[i], e1 = row_ptr[i + 1];
  float am0 = 0.f, av0 = 0.f, am1 = 0.f, av1 = 0.f;
  int e = e0;
  for (; e + 4 <= e1; e += 4) {
    const int s0 = csr[e], s1 = csr[e + 1], s2 = csr[e + 2], s3 = csr[e + 3];
    const unsigned q0 = m2v16[(size_t)s0 * 64 + lane];
    const unsigned q1 = m2v16[(size_t)s1 * 64 + lane];
    const unsigned q2 = m2v16[(size_t)s2 * 64 + lane];
    const unsigned q3 = m2v16[(size_t)s3 * 64 + lane];
    am0 += bflo(q0) + bflo(q1); am1 += bflo(q2) + bflo(q3);
    av0 += bfhi(q0) + bfhi(q1); av1 += bfhi(q2) + bfhi(q3);
  }
  for (; e < e1; e++) {
    const unsigned q0 = m2v16[(size_t)csr[e] * 64 + lane];
    am0 += bflo(q0); av0 += bfhi(q0);
  }
  const float mean = (am0 + am1) * norm1[i];
  const float var  = (av0 + av1) * norm2[i];
  const int b = i * 64 + lane;
  unsigned o0, o1;
  threefry2x32(0u, 42u, 0u, (unsigned)b, o0, o1);
  const float eps = bits_to_normal(o0 ^ o1);
  out[b] = eps * sqrtf(var + 1e-8f) + mean;
}

// ---------------- launch ----------------
extern "C" void kernel_launch(void* const* d_in, const int* in_sizes, int n_in,
                              void* d_out, int out_size, void* d_ws, size_t ws_size,
                              hipStream_t stream) {
  (void)in_sizes; (void)n_in; (void)out_size; (void)ws_size;
  const float* x   = (const float*)d_in[0];
  const int*   src = (const int*)d_in[1];
  const int*   dst = (const int*)d_in[2];
  const float* wm1 = (const float*)d_in[3];
  const float* wv1 = (const float*)d_in[4];
  const float* bm1 = (const float*)d_in[5];
  const float* bv1 = (const float*)d_in[6];
  const float* wm2 = (const float*)d_in[7];
  const float* wv2 = (const float*)d_in[8];
  const float* bm2 = (const float*)d_in[9];
  const float* bv2 = (const float*)d_in[10];
  float* out = (float*)d_out;

  char* base = (char*)d_ws;
  size_t off = 0;
  auto alloc = [&](size_t bytes) -> void* {
    void* p = base + off;
    off += (bytes + 255) & ~(size_t)255;
    return p;
  };
  int*      hist    = (int*)alloc((size_t)GN * 4);
  int*      row_ptr = (int*)alloc((size_t)(GN + 1) * 4);
  int*      fillc   = (int*)alloc((size_t)GN * 4);
  int*      csr     = (int*)alloc((size_t)GE * 4);
  float*    norm1   = (float*)alloc((size_t)GN * 4);
  float*    norm2   = (float*)alloc((size_t)GN * 4);
  unsigned* mv16    = (unsigned*)alloc((size_t)GN * 128 * 4);   // 51.2 MB bf16 {m,v} messages
  unsigned* hm      = (unsigned*)alloc((size_t)GN * 64 * 4);    // 25.6 MB f16 h_mean
  unsigned* hv      = (unsigned*)alloc((size_t)GN * 64 * 4);    // 25.6 MB f16 h_var
  f16*      p1m     = (f16*)alloc((size_t)256 * 128 * 2);
  f16*      p1v     = (f16*)alloc((size_t)256 * 128 * 2);
  f16*      p2m     = (f16*)alloc((size_t)128 * 64 * 2);
  f16*      p2v     = (f16*)alloc((size_t)128 * 64 * 2);
  unsigned* m2v16   = mv16;   // 25.6 MB needed; mv16 dead after agg1

  hipMemsetAsync(hist, 0, (size_t)GN * 4, stream);
  hipMemsetAsync(fillc, 0, (size_t)GN * 4, stream);

  pack_w_kernel<<<160, 64, 0, stream>>>(wm1, wv1, wm2, wv2, p1m, p1v, p2m, p2v);
  hist_kernel<<<(GE + 255) / 256, 256, 0, stream>>>(dst, hist);
  scan_kernel<<<1, 1024, 0, stream>>>(hist, row_ptr);
  norm_kernel<<<(GN + 255) / 256, 256, 0, stream>>>(hist, norm1, norm2);
  fill_kernel<<<(GE + 255) / 256, 256, 0, stream>>>(src, dst, row_ptr, fillc, csr);
  gemm1_kernel<<<(NT1 + 3) / 4, 256, 0, stream>>>(x, (const f16x8*)p1m, (const f16x8*)p1v,
                                                  bm1, bv1, norm1, norm2, mv16);
  agg1_kernel<<<GN / 4, 256, 0, stream>>>(row_ptr, csr, (const uint2*)mv16, norm1, norm2, hm, hv);
  gemm2_kernel<<<(NT1 + 3) / 4, 256, 0, stream>>>(hm, hv, (const f16x8*)p2m, (const f16x8*)p2v,
                                                  bm2, bv2, norm1, norm2, m2v16);
  agg2_reparam_kernel<<<GN / 4, 256, 0, stream>>>(row_ptr, csr, m2v16, norm1, norm2, out);
}